// Round 1
// 212.302 us; speedup vs baseline: 1.1774x; 1.1774x over previous
//
#include <hip/hip_runtime.h>

// Problem constants
#define D    128      // d+1
#define DM   127      // d
#define NP1  1024     // N+1
#define B    8
#define H    8
#define NL   4

// Workspace layout (float offsets)
#define WS_QF 0                         // [NL][H][128][128] padded Q * (1/N)
#define WS_PT (WS_QF + NL*H*D*D)        // [NL][H][128][128] padded+transposed P
#define WS_G  (WS_PT + NL*H*D*D)        // [B][128][128] reduced Gram
#define WS_GS (WS_G  + B*D*D)           // [B][8][128][128] shared: Gp partials, then Sp partials
#define WS_S  (WS_GS + B*8*D*D)         // [B][128][128] S = sum_h Sp (1/N folded into Qf)

// Async global->LDS, 16B per lane. LDS dest must be linear base + lane*16.
__device__ __forceinline__ void async16(const float* g, float* l)
{
    __builtin_amdgcn_global_load_lds(
        (const __attribute__((address_space(1))) void*)g,
        (__attribute__((address_space(3))) void*)l,
        16, 0, 0);
}

// ---------------------------------------------------------------------------
// Kernel 0 (once): pad/transpose ALL layers' params. Qf gets 1/N folded in.
// grid (512) x 256.  idx space: [NL][2][H][128][128] -> 4*262144 = 1,048,576
// ---------------------------------------------------------------------------
__global__ __launch_bounds__(256) void prep_kernel(
    const float* __restrict__ ap, float* __restrict__ Qf, float* __restrict__ Pt)
{
    const int t = threadIdx.x;
    const int base = blockIdx.x * 2048 + t * 8;
    const float inv = 1.0f / 1023.0f;
    #pragma unroll
    for (int e = 0; e < 8; ++e) {
        const int idx   = base + e;
        const int l     = idx >> 18;          // layer
        const int loc18 = idx & 262143;
        const int isP   = loc18 >> 17;
        const int local = loc18 & 131071;     // within [H][128][128]
        const int h = local >> 14;
        const int r = (local >> 7) & 127;
        const int c = local & 127;
        const float* apl = ap + (size_t)l * H * 2 * DM * DM;
        if (!isP) {
            float v = (r < DM && c < DM) ? apl[(h*2 + 1)*DM*DM + r*DM + c] * inv : 0.f;
            Qf[(size_t)l * H * D * D + local] = v;
        } else {
            float v;
            if (r < DM && c < DM)        v = apl[(h*2 + 0)*DM*DM + c*DM + r];
            else if (r == DM && c == DM) v = 1.f;
            else                         v = 0.f;
            Pt[(size_t)l * H * D * D + local] = v;
        }
    }
}

// ---------------------------------------------------------------------------
// Kernel 1: partial Grams. grid (8 chunks, 4 col-quarters, B) = 256 blocks.
// Async-stage the 128-token chunk; mask token 1023 by zeroing its LDS row.
// ---------------------------------------------------------------------------
__global__ __launch_bounds__(256) void gp_kernel(
    const float* __restrict__ Z, float* __restrict__ Gp)
{
    const int c = blockIdx.x;   // token chunk 0..7
    const int q = blockIdx.y;   // col quarter 0..3
    const int b = blockIdx.z;
    const int t = threadIdx.x;

    __shared__ float Zs[128 * 128];   // 64 KB

    const float* src = Z + ((size_t)b * NP1 + c * 128) * D;
    #pragma unroll
    for (int i = 0; i < 16; ++i)
        async16(src + (t + 256 * i) * 4, Zs + (t + 256 * i) * 4);
    __syncthreads();                  // drains vmcnt
    if (c == 7) {                     // key mask: zero token 1023 (row 127)
        if (t < 32) ((float4*)Zs)[4064 + t] = make_float4(0.f, 0.f, 0.f, 0.f);
        __syncthreads();
    }

    const int ty = t >> 3;            // 0..31 -> rows i0 = 4*ty
    const int tx = t & 7;             // 0..7  -> cols j0 = 32q + 4*tx
    const int i0 = ty * 4;
    const int j0 = q * 32 + tx * 4;

    float acc[4][4] = {};
    #pragma unroll 4
    for (int k = 0; k < 128; ++k) {
        const float4 a  = *(const float4*)&Zs[k * 128 + i0];
        const float4 cc = *(const float4*)&Zs[k * 128 + j0];
        acc[0][0] += a.x * cc.x; acc[0][1] += a.x * cc.y; acc[0][2] += a.x * cc.z; acc[0][3] += a.x * cc.w;
        acc[1][0] += a.y * cc.x; acc[1][1] += a.y * cc.y; acc[1][2] += a.y * cc.z; acc[1][3] += a.y * cc.w;
        acc[2][0] += a.z * cc.x; acc[2][1] += a.z * cc.y; acc[2][2] += a.z * cc.z; acc[2][3] += a.z * cc.w;
        acc[3][0] += a.w * cc.x; acc[3][1] += a.w * cc.y; acc[3][2] += a.w * cc.z; acc[3][3] += a.w * cc.w;
    }

    float* Gb = Gp + ((size_t)(b * 8 + c)) * D * D;
    #pragma unroll
    for (int r = 0; r < 4; ++r)
        *(float4*)&Gb[(i0 + r) * D + j0] = make_float4(acc[r][0], acc[r][1], acc[r][2], acc[r][3]);
}

// ---------------------------------------------------------------------------
// Kernel 2: G[b] = sum_c Gp[b][c]. grid (16, B) = 128 blocks.
// ---------------------------------------------------------------------------
__global__ __launch_bounds__(256) void gred_kernel(
    const float* __restrict__ Gp, float* __restrict__ G)
{
    const int b = blockIdx.y;
    const int idx4 = blockIdx.x * 256 + threadIdx.x;
    float4 sum = make_float4(0.f, 0.f, 0.f, 0.f);
    #pragma unroll
    for (int c = 0; c < 8; ++c) {
        const float4 v = ((const float4*)Gp)[(size_t)(b * 8 + c) * 4096 + idx4];
        sum.x += v.x; sum.y += v.y; sum.z += v.z; sum.w += v.w;
    }
    ((float4*)G)[(size_t)b * 4096 + idx4] = sum;
}

// ---------------------------------------------------------------------------
// Kernel 3: Sp[b][h] = (Qf_h @ G_b) @ Pt_h, fused, fully LDS-staged.
// grid (4 slices, H, B) = 256 blocks. LDS = 16 + 64 + 64 = 144 KB.
// Only 3 barriers per block; Pt arrives under phase-1 compute (vmcnt(16)).
// ---------------------------------------------------------------------------
__global__ __launch_bounds__(256) void ts_kernel(
    const float* __restrict__ Qf, const float* __restrict__ Pt,
    const float* __restrict__ G, float* __restrict__ Sp)
{
    const int s = blockIdx.x;   // 0..3 (row slice of 32)
    const int h = blockIdx.y;
    const int b = blockIdx.z;
    const int t = threadIdx.x;
    const int ty = t >> 4;      // 0..15 -> local rows ty, ty+16
    const int tx = t & 15;
    const int j0 = 4 * tx;
    const int j1 = 64 + 4 * tx;

    __shared__ float Qs[32 * 128];    // 16 KB
    __shared__ float GT[128 * 128];   // 64 KB: G, then reused for T (rows 0..31)
    __shared__ float Ps[128 * 128];   // 64 KB

    // ---- issue all staging async: Q slice, full G, full Pt (in that order) ----
    const float* qsrc = Qf + ((size_t)h * D + s * 32) * D;
    #pragma unroll
    for (int i = 0; i < 4; ++i)  async16(qsrc + (t + 256 * i) * 4, Qs + (t + 256 * i) * 4);
    const float* gsrc = G + (size_t)b * D * D;
    #pragma unroll
    for (int i = 0; i < 16; ++i) async16(gsrc + (t + 256 * i) * 4, GT + (t + 256 * i) * 4);
    const float* psrc = Pt + (size_t)h * D * D;
    #pragma unroll
    for (int i = 0; i < 16; ++i) async16(psrc + (t + 256 * i) * 4, Ps + (t + 256 * i) * 4);

    // wait for Q+G only (16 Pt loads may remain in flight), then barrier
    asm volatile("s_waitcnt vmcnt(16)" ::: "memory");
    __builtin_amdgcn_s_barrier();
    asm volatile("" ::: "memory");

    // ---- phase 1: T(32x128) = Qs @ G ----
    float acc[2][8] = {};
    #pragma unroll 2
    for (int k4 = 0; k4 < 32; ++k4) {
        const float4 q0 = *(const float4*)&Qs[ty * 128 + k4 * 4];
        const float4 q1 = *(const float4*)&Qs[(ty + 16) * 128 + k4 * 4];
        #pragma unroll
        for (int u = 0; u < 4; ++u) {
            const float qa = ((const float*)&q0)[u];
            const float qb = ((const float*)&q1)[u];
            const float4 g0 = *(const float4*)&GT[(k4 * 4 + u) * 128 + j0];
            const float4 g1 = *(const float4*)&GT[(k4 * 4 + u) * 128 + j1];
            acc[0][0] += qa * g0.x; acc[0][1] += qa * g0.y; acc[0][2] += qa * g0.z; acc[0][3] += qa * g0.w;
            acc[0][4] += qa * g1.x; acc[0][5] += qa * g1.y; acc[0][6] += qa * g1.z; acc[0][7] += qa * g1.w;
            acc[1][0] += qb * g0.x; acc[1][1] += qb * g0.y; acc[1][2] += qb * g0.z; acc[1][3] += qb * g0.w;
            acc[1][4] += qb * g1.x; acc[1][5] += qb * g1.y; acc[1][6] += qb * g1.z; acc[1][7] += qb * g1.w;
        }
    }

    __syncthreads();   // all reads of G done (also drains remaining Pt loads)
    *(float4*)&GT[ty * 128 + j0]        = make_float4(acc[0][0], acc[0][1], acc[0][2], acc[0][3]);
    *(float4*)&GT[ty * 128 + j1]        = make_float4(acc[0][4], acc[0][5], acc[0][6], acc[0][7]);
    *(float4*)&GT[(ty + 16) * 128 + j0] = make_float4(acc[1][0], acc[1][1], acc[1][2], acc[1][3]);
    *(float4*)&GT[(ty + 16) * 128 + j1] = make_float4(acc[1][4], acc[1][5], acc[1][6], acc[1][7]);
    __syncthreads();

    // ---- phase 2: Sp rows = T @ Pt ----
    float bcc[2][8] = {};
    #pragma unroll 2
    for (int k4 = 0; k4 < 32; ++k4) {
        const float4 t0 = *(const float4*)&GT[ty * 128 + k4 * 4];
        const float4 t1 = *(const float4*)&GT[(ty + 16) * 128 + k4 * 4];
        #pragma unroll
        for (int u = 0; u < 4; ++u) {
            const float ta = ((const float*)&t0)[u];
            const float tb = ((const float*)&t1)[u];
            const float4 p0 = *(const float4*)&Ps[(k4 * 4 + u) * 128 + j0];
            const float4 p1 = *(const float4*)&Ps[(k4 * 4 + u) * 128 + j1];
            bcc[0][0] += ta * p0.x; bcc[0][1] += ta * p0.y; bcc[0][2] += ta * p0.z; bcc[0][3] += ta * p0.w;
            bcc[0][4] += ta * p1.x; bcc[0][5] += ta * p1.y; bcc[0][6] += ta * p1.z; bcc[0][7] += ta * p1.w;
            bcc[1][0] += tb * p0.x; bcc[1][1] += tb * p0.y; bcc[1][2] += tb * p0.z; bcc[1][3] += tb * p0.w;
            bcc[1][4] += tb * p1.x; bcc[1][5] += tb * p1.y; bcc[1][6] += tb * p1.z; bcc[1][7] += tb * p1.w;
        }
    }

    float* Sb = Sp + ((size_t)(b * 8 + h)) * D * D;
    const int r0 = s * 32 + ty;
    const int r1 = r0 + 16;
    *(float4*)&Sb[r0 * D + j0] = make_float4(bcc[0][0], bcc[0][1], bcc[0][2], bcc[0][3]);
    *(float4*)&Sb[r0 * D + j1] = make_float4(bcc[0][4], bcc[0][5], bcc[0][6], bcc[0][7]);
    *(float4*)&Sb[r1 * D + j0] = make_float4(bcc[1][0], bcc[1][1], bcc[1][2], bcc[1][3]);
    *(float4*)&Sb[r1 * D + j1] = make_float4(bcc[1][4], bcc[1][5], bcc[1][6], bcc[1][7]);
}

// ---------------------------------------------------------------------------
// Kernel 4: S[b] = sum_h Sp[b][h] (1/N already folded into Qf). grid (16, B).
// ---------------------------------------------------------------------------
__global__ __launch_bounds__(256) void sred_kernel(
    const float* __restrict__ Sp, float* __restrict__ S)
{
    const int b = blockIdx.y;
    const int idx4 = blockIdx.x * 256 + threadIdx.x;
    float4 sum = make_float4(0.f, 0.f, 0.f, 0.f);
    #pragma unroll
    for (int h = 0; h < 8; ++h) {
        const float4 v = ((const float4*)Sp)[(size_t)(b * 8 + h) * 4096 + idx4];
        sum.x += v.x; sum.y += v.y; sum.z += v.z; sum.w += v.w;
    }
    ((float4*)S)[(size_t)b * 4096 + idx4] = sum;
}

// ---------------------------------------------------------------------------
// Kernel 5: Zout = Zin + Zin @ S. grid (32, B). Full S staged once (async),
// single barrier, uninterrupted K loop.
// ---------------------------------------------------------------------------
__global__ __launch_bounds__(256) void z_kernel(
    const float* __restrict__ Zin, const float* __restrict__ S, float* __restrict__ Zout)
{
    const int sblk = blockIdx.x;   // 0..31
    const int b = blockIdx.y;
    const int t = threadIdx.x;
    const int ty = t >> 3;         // 0..31 -> row
    const int tx = t & 7;          // cols 4tx + 32jj

    __shared__ float Zs[32 * 132]; // padded: conflict-free scalar row reads
    __shared__ float Ss[128 * 128];

    const float* Sb = S + (size_t)b * D * D;
    #pragma unroll
    for (int i = 0; i < 16; ++i)
        async16(Sb + (t + 256 * i) * 4, Ss + (t + 256 * i) * 4);

    const float* Zrow0 = Zin + ((size_t)b * NP1 + sblk * 32) * D;
    for (int q = t; q < 32 * 32; q += 256) {
        const int r = q >> 5, c4 = q & 31;
        *(float4*)&Zs[r * 132 + c4 * 4] = ((const float4*)(Zrow0 + r * D))[c4];
    }
    __syncthreads();   // drains vmcnt (S) + lgkm (Zs)

    float acc[16];
    #pragma unroll
    for (int q = 0; q < 16; ++q) acc[q] = 0.f;

    #pragma unroll 2
    for (int k4 = 0; k4 < 32; ++k4) {
        const float4 zq = *(const float4*)&Zs[ty * 132 + k4 * 4];
        #pragma unroll
        for (int u = 0; u < 4; ++u) {
            const float zv = ((const float*)&zq)[u];
            #pragma unroll
            for (int jj = 0; jj < 4; ++jj) {
                const float4 sv = *(const float4*)&Ss[(k4 * 4 + u) * 128 + 4 * tx + 32 * jj];
                acc[jj * 4 + 0] += zv * sv.x;
                acc[jj * 4 + 1] += zv * sv.y;
                acc[jj * 4 + 2] += zv * sv.z;
                acc[jj * 4 + 3] += zv * sv.w;
            }
        }
    }

    float* Orow = Zout + ((size_t)b * NP1 + sblk * 32 + ty) * D;
    #pragma unroll
    for (int jj = 0; jj < 4; ++jj) {
        const int col = 4 * tx + 32 * jj;
        const float4 zr = *(const float4*)&Zs[ty * 132 + col];
        float4 o;
        o.x = zr.x + acc[jj * 4 + 0];
        o.y = zr.y + acc[jj * 4 + 1];
        o.z = zr.z + acc[jj * 4 + 2];
        o.w = zr.w + acc[jj * 4 + 3];
        *(float4*)(Orow + col) = o;
    }
}

// ---------------------------------------------------------------------------
extern "C" void kernel_launch(void* const* d_in, const int* in_sizes, int n_in,
                              void* d_out, int out_size, void* d_ws, size_t ws_size,
                              hipStream_t stream)
{
    const float* Z0 = (const float*)d_in[0];
    const float* ap = (const float*)d_in[1];
    float* out = (float*)d_out;
    float* ws  = (float*)d_ws;

    float* Qf = ws + WS_QF;
    float* Pt = ws + WS_PT;
    float* G  = ws + WS_G;
    float* GS = ws + WS_GS;   // Gp then Sp (disjoint lifetimes within a layer)
    float* S  = ws + WS_S;

    hipLaunchKernelGGL(prep_kernel, dim3(512), dim3(256), 0, stream, ap, Qf, Pt);

    const float* Zcur = Z0;
    for (int l = 0; l < NL; ++l) {
        const float* Qfl = Qf + (size_t)l * H * D * D;
        const float* Ptl = Pt + (size_t)l * H * D * D;
        hipLaunchKernelGGL(gp_kernel,   dim3(8, 4, B), dim3(256), 0, stream, Zcur, GS);
        hipLaunchKernelGGL(gred_kernel, dim3(16, B),   dim3(256), 0, stream, GS, G);
        hipLaunchKernelGGL(ts_kernel,   dim3(4, H, B), dim3(256), 0, stream, Qfl, Ptl, G, GS);
        hipLaunchKernelGGL(sred_kernel, dim3(16, B),   dim3(256), 0, stream, GS, S);
        hipLaunchKernelGGL(z_kernel,    dim3(32, B),   dim3(256), 0, stream, Zcur, S, out);
        Zcur = out;
    }
}